// Round 7
// baseline (251.228 us; speedup 1.0000x reference)
//
#include <hip/hip_runtime.h>
#include <math.h>

#define SCALING 0.125f

typedef __attribute__((ext_vector_type(8))) short short8;
typedef __attribute__((ext_vector_type(4))) float f32x4;

// round-to-nearest-even fp32 -> bf16
static __device__ __forceinline__ unsigned short bf16r(float x) {
  unsigned int u = __float_as_uint(x);
  u += 0x7fffu + ((u >> 16) & 1u);
  return (unsigned short)(u >> 16);
}
static __device__ __forceinline__ float bf16f(unsigned short h) {
  return __uint_as_float(((unsigned int)h) << 16);
}
// pack two fp32 -> bf16x2 via v_perm_b32 merge
static __device__ __forceinline__ unsigned int pk_bf16(float lo, float hi) {
  unsigned int ua = __float_as_uint(lo);
  unsigned int ub = __float_as_uint(hi);
  ua += 0x7fffu + ((ua >> 16) & 1u);
  ub += 0x7fffu + ((ub >> 16) & 1u);
  return __builtin_amdgcn_perm(ub, ua, 0x07060302u);
}
// fp32x4 -> bf16 hi + residual lo
static __device__ __forceinline__ void split4(float4 x, ushort4& h, ushort4& l) {
  h.x = bf16r(x.x); l.x = bf16r(x.x - bf16f(h.x));
  h.y = bf16r(x.y); l.y = bf16r(x.y - bf16f(h.y));
  h.z = bf16r(x.z); l.z = bf16r(x.z - bf16f(h.z));
  h.w = bf16r(x.w); l.w = bf16r(x.w - bf16f(h.w));
}
union U4S8 { uint4 u; short8 s; };

// ---------------------------------------------------------------------------
// Kernel A: in-projection GEMM, hi/lo bf16 MFMA (Ahi*Bhi + Ahi*Blo + Alo*Bhi,
// fp32-accurate to ~2^-18). fp32 tiles loaded coalesced, converted in-reg,
// staged to LDS; fragment/D mapping identical to the R6-verified projmm.
// Epilogue scatter: j<512: q->qh fp32*SCALING; j<1024: k->kh fp32;
//                   j<1536: v->vh bf16.
// ---------------------------------------------------------------------------
__global__ __launch_bounds__(256)
void projmm_kernel(const float* __restrict__ query,
                   const float* __restrict__ key,
                   const float* __restrict__ value,
                   const float* __restrict__ W,
                   const float* __restrict__ bias,
                   float* __restrict__ qh, float* __restrict__ kh,
                   unsigned short* __restrict__ vh) {
  __shared__ __align__(16) unsigned short Ah[64 * 72];
  __shared__ __align__(16) unsigned short Al[64 * 72];
  __shared__ __align__(16) unsigned short Bh[64 * 72];
  __shared__ __align__(16) unsigned short Bl[64 * 72];
  const int n0 = blockIdx.x * 64;  // 0..1535
  const int g = n0 >> 9;           // 0=q,1=k,2=v
  const float* __restrict__ X = (g == 0) ? query : (g == 1) ? key : value;
  const int m0 = blockIdx.y * 64;
  const int tid = threadIdx.x;
  const int w = tid >> 6, lane = tid & 63;
  const int quad = lane >> 4, n15 = lane & 15;
  const int srow = tid >> 2;        // 0..63
  const int scol = (tid & 3) * 16;  // 0,16,32,48

  f32x4 acc[4];
#pragma unroll
  for (int nt = 0; nt < 4; ++nt) acc[nt] = (f32x4){0.f, 0.f, 0.f, 0.f};

  float4 av[4], bv[4];
#pragma unroll
  for (int jj = 0; jj < 4; ++jj) {
    av[jj] = *(const float4*)&X[(m0 + srow) * 512 + scol + 4 * jj];
    bv[jj] = *(const float4*)&W[(n0 + srow) * 512 + scol + 4 * jj];
  }

  for (int k0 = 0; k0 < 512; k0 += 64) {
    __syncthreads();  // protect previous chunk's fragment reads
#pragma unroll
    for (int jj = 0; jj < 4; ++jj) {
      ushort4 hh, ll;
      split4(av[jj], hh, ll);
      *(ushort4*)&Ah[srow * 72 + scol + 4 * jj] = hh;
      *(ushort4*)&Al[srow * 72 + scol + 4 * jj] = ll;
      split4(bv[jj], hh, ll);
      *(ushort4*)&Bh[srow * 72 + scol + 4 * jj] = hh;
      *(ushort4*)&Bl[srow * 72 + scol + 4 * jj] = ll;
    }
    __syncthreads();
    if (k0 + 64 < 512) {  // prefetch next chunk during MFMA
#pragma unroll
      for (int jj = 0; jj < 4; ++jj) {
        av[jj] = *(const float4*)&X[(m0 + srow) * 512 + k0 + 64 + scol + 4 * jj];
        bv[jj] = *(const float4*)&W[(n0 + srow) * 512 + k0 + 64 + scol + 4 * jj];
      }
    }
#pragma unroll
    for (int kk = 0; kk < 2; ++kk) {
      short8 ah = *(const short8*)&Ah[(w * 16 + n15) * 72 + kk * 32 + quad * 8];
      short8 al = *(const short8*)&Al[(w * 16 + n15) * 72 + kk * 32 + quad * 8];
#pragma unroll
      for (int nt = 0; nt < 4; ++nt) {
        short8 bh = *(const short8*)&Bh[(nt * 16 + n15) * 72 + kk * 32 + quad * 8];
        short8 bl = *(const short8*)&Bl[(nt * 16 + n15) * 72 + kk * 32 + quad * 8];
        acc[nt] = __builtin_amdgcn_mfma_f32_16x16x32_bf16(ah, bh, acc[nt], 0, 0, 0);
        acc[nt] = __builtin_amdgcn_mfma_f32_16x16x32_bf16(ah, bl, acc[nt], 0, 0, 0);
        acc[nt] = __builtin_amdgcn_mfma_f32_16x16x32_bf16(al, bh, acc[nt], 0, 0, 0);
      }
    }
  }

#pragma unroll
  for (int nt = 0; nt < 4; ++nt) {
    const int j = n0 + nt * 16 + n15;
    const int jj = j & 511;
    const int head = jj >> 6;
    const int hd = jj & 63;
    const float bj = bias[j];
#pragma unroll
    for (int r = 0; r < 4; ++r) {
      const int row = m0 + w * 16 + quad * 4 + r;
      const int t = row >> 3;
      const int batch = row & 7;
      const int i = batch * 8 + head;
      const int idx = ((i << 7) + t) * 64 + hd;
      const float val = acc[nt][r] + bj;
      if (g == 0)      qh[idx] = val * SCALING;
      else if (g == 1) kh[idx] = val;
      else             vh[idx] = bf16r(val);
    }
  }
}

// ---------------------------------------------------------------------------
// Kernel B: one block per (batch, a, b-half), loops 8 heads. Vs staged in LDS
// (shared across waves); B-fragments (k[b,:]*qa) built IN-REGISTER from
// direct L2 loads — no Ks LDS, no K staging. Bias fragment preloaded once.
// ---------------------------------------------------------------------------
__global__ __launch_bounds__(256)
void score_kernel(const float* __restrict__ qh,
                  const float* __restrict__ kh,
                  const unsigned short* __restrict__ vh,
                  const float* __restrict__ cbias,
                  float* __restrict__ fused) {
  __shared__ __align__(16) unsigned short Vs[128 * 72];

  const int bid = blockIdx.x;  // (batch*128 + a)*2 + bh
  const int bh = bid & 1;
  const int ab = bid >> 1;
  const int batch = ab >> 7;
  const int a = ab & 127;
  const int tid = threadIdx.x;
  const int w = tid >> 6;
  const int lane = tid & 63;
  const int quad = lane >> 4;
  const int n15 = lane & 15;
  const int col8 = (tid & 7) * 8;
  const int bglob = bh * 64 + w * 16 + n15;

  // preload bias fragment (head-invariant) into registers
  const float* __restrict__ bp = cbias + (size_t)ab * 16384;
  f32x4 biasReg[8];
#pragma unroll
  for (int ic = 0; ic < 8; ++ic)
    biasReg[ic] = *(const f32x4*)&bp[bglob * 128 + ic * 16 + quad * 4];

  for (int h = 0; h < 8; ++h) {
    const int i = batch * 8 + h;
    const uint4* __restrict__ vb4 = (const uint4*)(vh + (size_t)i * 8192);
    const float* __restrict__ kr = kh + (size_t)i * 8192 + bglob * 64;
    const float* __restrict__ qa = qh + ((size_t)i * 128 + a) * 64;

    // V tile -> regs (LDS write after barrier)
    uint4 vreg[4];
#pragma unroll
    for (int j = 0; j < 4; ++j) vreg[j] = vb4[j * 256 + tid];

    // B-frags in-register: k[bglob][hd]*qa[hd], hd = quad*8..+8 (+32)
    f32x4 k0 = *(const f32x4*)&kr[quad * 8];
    f32x4 k1 = *(const f32x4*)&kr[quad * 8 + 4];
    f32x4 k2 = *(const f32x4*)&kr[32 + quad * 8];
    f32x4 k3 = *(const f32x4*)&kr[32 + quad * 8 + 4];
    k0 *= *(const f32x4*)&qa[quad * 8];
    k1 *= *(const f32x4*)&qa[quad * 8 + 4];
    k2 *= *(const f32x4*)&qa[32 + quad * 8];
    k3 *= *(const f32x4*)&qa[32 + quad * 8 + 4];
    U4S8 b0, b1;
    b0.u.x = pk_bf16(k0[0], k0[1]); b0.u.y = pk_bf16(k0[2], k0[3]);
    b0.u.z = pk_bf16(k1[0], k1[1]); b0.u.w = pk_bf16(k1[2], k1[3]);
    b1.u.x = pk_bf16(k2[0], k2[1]); b1.u.y = pk_bf16(k2[2], k2[3]);
    b1.u.z = pk_bf16(k3[0], k3[1]); b1.u.w = pk_bf16(k3[2], k3[3]);

    __syncthreads();  // previous head's Vs reads complete
#pragma unroll
    for (int j = 0; j < 4; ++j)
      *(uint4*)&Vs[((j * 256 + tid) >> 3) * 72 + col8] = vreg[j];
    __syncthreads();

    f32x4 acc[8];
#pragma unroll
    for (int ic = 0; ic < 8; ++ic) acc[ic] = (f32x4){0.f, 0.f, 0.f, 0.f};
#pragma unroll
    for (int ic = 0; ic < 8; ++ic) {
      short8 a0 = *(const short8*)&Vs[(ic * 16 + n15) * 72 + quad * 8];
      short8 a1 = *(const short8*)&Vs[(ic * 16 + n15) * 72 + 32 + quad * 8];
      acc[ic] = __builtin_amdgcn_mfma_f32_16x16x32_bf16(a0, b0.s, acc[ic], 0, 0, 0);
      acc[ic] = __builtin_amdgcn_mfma_f32_16x16x32_bf16(a1, b1.s, acc[ic], 0, 0, 0);
    }

    float fsum = 0.f, fmx = -INFINITY;
#pragma unroll
    for (int ic = 0; ic < 8; ++ic) {
#pragma unroll
      for (int r = 0; r < 4; ++r) {
        const float v = acc[ic][r] + biasReg[ic][r];
        fsum += v;
        fmx = fmaxf(fmx, v);
      }
    }
    fsum += __shfl_xor(fsum, 16, 64);
    fmx = fmaxf(fmx, __shfl_xor(fmx, 16, 64));
    fsum += __shfl_xor(fsum, 32, 64);
    fmx = fmaxf(fmx, __shfl_xor(fmx, 32, 64));
    if (quad == 0)
      fused[((size_t)i * 128 + a) * 128 + bglob] = fsum * (1.0f / 128.0f) + fmx;
  }
}

// ---------------------------------------------------------------------------
// Kernel C: softmax over b + attn[i,a,:] = sum_b w[b]*q[i,b,:]  (verified)
// ---------------------------------------------------------------------------
__global__ __launch_bounds__(64)
void softmax_attn_kernel(const float* __restrict__ fused,
                         const float* __restrict__ qh,
                         float* __restrict__ attn) {
  const int bid = blockIdx.x;  // i*128 + a
  const int i = bid >> 7;
  const int a = bid & 127;
  const int lane = threadIdx.x;
  const float* __restrict__ fr = fused + (size_t)bid * 128;
  float f0 = fr[lane], f1 = fr[lane + 64];
  float m = fmaxf(f0, f1);
#pragma unroll
  for (int off = 32; off >= 1; off >>= 1) m = fmaxf(m, __shfl_xor(m, off, 64));
  const float e0 = expf(f0 - m), e1 = expf(f1 - m);
  float s = e0 + e1;
#pragma unroll
  for (int off = 32; off >= 1; off >>= 1) s += __shfl_xor(s, off, 64);
  const float inv = 1.0f / s;
  __shared__ float w[128];
  w[lane] = e0 * inv;
  w[lane + 64] = e1 * inv;
  __syncthreads();
  const float* __restrict__ qp = qh + (size_t)i * 128 * 64 + lane;
  float acc = 0.0f;
#pragma unroll 4
  for (int b = 0; b < 128; b++) acc = fmaf(w[b], qp[b * 64], acc);
  const int batch = i >> 3, head = i & 7;
  attn[((size_t)a * 8 + batch) * 512 + head * 64 + lane] = acc;
}

// ---------------------------------------------------------------------------
// Kernel D: output projection, same hi/lo MFMA structure as projmm.
// ---------------------------------------------------------------------------
__global__ __launch_bounds__(256)
void outmm_kernel(const float* __restrict__ Xa,
                  const float* __restrict__ W,
                  const float* __restrict__ bias,
                  float* __restrict__ out) {
  __shared__ __align__(16) unsigned short Ah[64 * 72];
  __shared__ __align__(16) unsigned short Al[64 * 72];
  __shared__ __align__(16) unsigned short Bh[64 * 72];
  __shared__ __align__(16) unsigned short Bl[64 * 72];
  const int n0 = blockIdx.x * 64;  // 0..511
  const int m0 = blockIdx.y * 64;
  const int tid = threadIdx.x;
  const int w = tid >> 6, lane = tid & 63;
  const int quad = lane >> 4, n15 = lane & 15;
  const int srow = tid >> 2;
  const int scol = (tid & 3) * 16;

  f32x4 acc[4];
#pragma unroll
  for (int nt = 0; nt < 4; ++nt) acc[nt] = (f32x4){0.f, 0.f, 0.f, 0.f};

  float4 av[4], bv[4];
#pragma unroll
  for (int jj = 0; jj < 4; ++jj) {
    av[jj] = *(const float4*)&Xa[(m0 + srow) * 512 + scol + 4 * jj];
    bv[jj] = *(const float4*)&W[(n0 + srow) * 512 + scol + 4 * jj];
  }

  for (int k0 = 0; k0 < 512; k0 += 64) {
    __syncthreads();
#pragma unroll
    for (int jj = 0; jj < 4; ++jj) {
      ushort4 hh, ll;
      split4(av[jj], hh, ll);
      *(ushort4*)&Ah[srow * 72 + scol + 4 * jj] = hh;
      *(ushort4*)&Al[srow * 72 + scol + 4 * jj] = ll;
      split4(bv[jj], hh, ll);
      *(ushort4*)&Bh[srow * 72 + scol + 4 * jj] = hh;
      *(ushort4*)&Bl[srow * 72 + scol + 4 * jj] = ll;
    }
    __syncthreads();
    if (k0 + 64 < 512) {
#pragma unroll
      for (int jj = 0; jj < 4; ++jj) {
        av[jj] = *(const float4*)&Xa[(m0 + srow) * 512 + k0 + 64 + scol + 4 * jj];
        bv[jj] = *(const float4*)&W[(n0 + srow) * 512 + k0 + 64 + scol + 4 * jj];
      }
    }
#pragma unroll
    for (int kk = 0; kk < 2; ++kk) {
      short8 ah = *(const short8*)&Ah[(w * 16 + n15) * 72 + kk * 32 + quad * 8];
      short8 al = *(const short8*)&Al[(w * 16 + n15) * 72 + kk * 32 + quad * 8];
#pragma unroll
      for (int nt = 0; nt < 4; ++nt) {
        short8 bh = *(const short8*)&Bh[(nt * 16 + n15) * 72 + kk * 32 + quad * 8];
        short8 bl = *(const short8*)&Bl[(nt * 16 + n15) * 72 + kk * 32 + quad * 8];
        acc[nt] = __builtin_amdgcn_mfma_f32_16x16x32_bf16(ah, bh, acc[nt], 0, 0, 0);
        acc[nt] = __builtin_amdgcn_mfma_f32_16x16x32_bf16(ah, bl, acc[nt], 0, 0, 0);
        acc[nt] = __builtin_amdgcn_mfma_f32_16x16x32_bf16(al, bh, acc[nt], 0, 0, 0);
      }
    }
  }

#pragma unroll
  for (int nt = 0; nt < 4; ++nt) {
    const int j = n0 + nt * 16 + n15;
    const float bj = bias[j];
#pragma unroll
    for (int r = 0; r < 4; ++r) {
      const int row = m0 + w * 16 + quad * 4 + r;
      out[(size_t)row * 512 + j] = acc[nt][r] + bj;
    }
  }
}

extern "C" void kernel_launch(void* const* d_in, const int* in_sizes, int n_in,
                              void* d_out, int out_size, void* d_ws,
                              size_t ws_size, hipStream_t stream) {
  const float* query = (const float*)d_in[0];
  const float* key   = (const float*)d_in[1];
  const float* value = (const float*)d_in[2];
  const float* cbias = (const float*)d_in[3];
  const float* W     = (const float*)d_in[4];
  const float* pb    = (const float*)d_in[5];
  const float* out_w = (const float*)d_in[6];
  const float* out_b = (const float*)d_in[7];
  float* out = (float*)d_out;

  float* ws = (float*)d_ws;
  float* qh = ws;                                        // 524288 f
  float* kh = ws + 524288;                               // 524288 f
  unsigned short* vh = (unsigned short*)(ws + 1048576);  // 524288 bf16
  float* fusedb = ws + 1048576 + 262144;                 // 1048576 f
  float* attn = fusedb + 1048576;                        // 524288 f

  projmm_kernel<<<dim3(24, 16), 256, 0, stream>>>(query, key, value, W, pb,
                                                  qh, kh, vh);
  score_kernel<<<2048, 256, 0, stream>>>(qh, kh, vh, cbias, fusedb);
  softmax_attn_kernel<<<8192, 64, 0, stream>>>(fusedb, qh, attn);
  outmm_kernel<<<dim3(8, 16), 256, 0, stream>>>(attn, out_w, out_b, out);
}

// Round 8
// 202.009 us; speedup vs baseline: 1.2436x; 1.2436x over previous
//
#include <hip/hip_runtime.h>
#include <math.h>

#define SCALING 0.125f

typedef __attribute__((ext_vector_type(8))) short short8;
typedef __attribute__((ext_vector_type(4))) float f32x4;

// round-to-nearest-even fp32 -> bf16
static __device__ __forceinline__ unsigned short bf16r(float x) {
  unsigned int u = __float_as_uint(x);
  u += 0x7fffu + ((u >> 16) & 1u);
  return (unsigned short)(u >> 16);
}
static __device__ __forceinline__ float bf16f(unsigned short h) {
  return __uint_as_float(((unsigned int)h) << 16);
}
// pack two fp32 -> bf16x2 via v_perm_b32 merge
static __device__ __forceinline__ unsigned int pk_bf16(float lo, float hi) {
  unsigned int ua = __float_as_uint(lo);
  unsigned int ub = __float_as_uint(hi);
  ua += 0x7fffu + ((ua >> 16) & 1u);
  ub += 0x7fffu + ((ub >> 16) & 1u);
  return __builtin_amdgcn_perm(ub, ua, 0x07060302u);
}
// fp32x4 -> bf16 hi + residual lo
static __device__ __forceinline__ void split4(float4 x, ushort4& h, ushort4& l) {
  h.x = bf16r(x.x); l.x = bf16r(x.x - bf16f(h.x));
  h.y = bf16r(x.y); l.y = bf16r(x.y - bf16f(h.y));
  h.z = bf16r(x.z); l.z = bf16r(x.z - bf16f(h.z));
  h.w = bf16r(x.w); l.w = bf16r(x.w - bf16f(h.w));
}
union U4S8 { uint4 u; short8 s; };

// ---------------------------------------------------------------------------
// Kernel A: in-projection GEMM, hi/lo bf16 MFMA (verified R7). LDS-staged,
// fused fp32->hi/lo conversion, software-pipelined.
// ---------------------------------------------------------------------------
__global__ __launch_bounds__(256)
void projmm_kernel(const float* __restrict__ query,
                   const float* __restrict__ key,
                   const float* __restrict__ value,
                   const float* __restrict__ W,
                   const float* __restrict__ bias,
                   float* __restrict__ qh, float* __restrict__ kh,
                   unsigned short* __restrict__ vh) {
  __shared__ __align__(16) unsigned short Ah[64 * 72];
  __shared__ __align__(16) unsigned short Al[64 * 72];
  __shared__ __align__(16) unsigned short Bh[64 * 72];
  __shared__ __align__(16) unsigned short Bl[64 * 72];
  const int n0 = blockIdx.x * 64;  // 0..1535
  const int g = n0 >> 9;           // 0=q,1=k,2=v
  const float* __restrict__ X = (g == 0) ? query : (g == 1) ? key : value;
  const int m0 = blockIdx.y * 64;
  const int tid = threadIdx.x;
  const int w = tid >> 6, lane = tid & 63;
  const int quad = lane >> 4, n15 = lane & 15;
  const int srow = tid >> 2;        // 0..63
  const int scol = (tid & 3) * 16;  // 0,16,32,48

  f32x4 acc[4];
#pragma unroll
  for (int nt = 0; nt < 4; ++nt) acc[nt] = (f32x4){0.f, 0.f, 0.f, 0.f};

  float4 av[4], bv[4];
#pragma unroll
  for (int jj = 0; jj < 4; ++jj) {
    av[jj] = *(const float4*)&X[(m0 + srow) * 512 + scol + 4 * jj];
    bv[jj] = *(const float4*)&W[(n0 + srow) * 512 + scol + 4 * jj];
  }

  for (int k0 = 0; k0 < 512; k0 += 64) {
    __syncthreads();  // protect previous chunk's fragment reads
#pragma unroll
    for (int jj = 0; jj < 4; ++jj) {
      ushort4 hh, ll;
      split4(av[jj], hh, ll);
      *(ushort4*)&Ah[srow * 72 + scol + 4 * jj] = hh;
      *(ushort4*)&Al[srow * 72 + scol + 4 * jj] = ll;
      split4(bv[jj], hh, ll);
      *(ushort4*)&Bh[srow * 72 + scol + 4 * jj] = hh;
      *(ushort4*)&Bl[srow * 72 + scol + 4 * jj] = ll;
    }
    __syncthreads();
    if (k0 + 64 < 512) {  // prefetch next chunk during MFMA
#pragma unroll
      for (int jj = 0; jj < 4; ++jj) {
        av[jj] = *(const float4*)&X[(m0 + srow) * 512 + k0 + 64 + scol + 4 * jj];
        bv[jj] = *(const float4*)&W[(n0 + srow) * 512 + k0 + 64 + scol + 4 * jj];
      }
    }
#pragma unroll
    for (int kk = 0; kk < 2; ++kk) {
      short8 ah = *(const short8*)&Ah[(w * 16 + n15) * 72 + kk * 32 + quad * 8];
      short8 al = *(const short8*)&Al[(w * 16 + n15) * 72 + kk * 32 + quad * 8];
#pragma unroll
      for (int nt = 0; nt < 4; ++nt) {
        short8 bh = *(const short8*)&Bh[(nt * 16 + n15) * 72 + kk * 32 + quad * 8];
        short8 bl = *(const short8*)&Bl[(nt * 16 + n15) * 72 + kk * 32 + quad * 8];
        acc[nt] = __builtin_amdgcn_mfma_f32_16x16x32_bf16(ah, bh, acc[nt], 0, 0, 0);
        acc[nt] = __builtin_amdgcn_mfma_f32_16x16x32_bf16(ah, bl, acc[nt], 0, 0, 0);
        acc[nt] = __builtin_amdgcn_mfma_f32_16x16x32_bf16(al, bh, acc[nt], 0, 0, 0);
      }
    }
  }

#pragma unroll
  for (int nt = 0; nt < 4; ++nt) {
    const int j = n0 + nt * 16 + n15;
    const int jj = j & 511;
    const int head = jj >> 6;
    const int hd = jj & 63;
    const float bj = bias[j];
#pragma unroll
    for (int r = 0; r < 4; ++r) {
      const int row = m0 + w * 16 + quad * 4 + r;
      const int t = row >> 3;
      const int batch = row & 7;
      const int i = batch * 8 + head;
      const int idx = ((i << 7) + t) * 64 + hd;
      const float val = acc[nt][r] + bj;
      if (g == 0)      qh[idx] = val * SCALING;
      else if (g == 1) kh[idx] = val;
      else             vh[idx] = bf16r(val);
    }
  }
}

// ---------------------------------------------------------------------------
// Kernel B: one block per (batch, a, b-half), loops 8 heads.
// Vs in LDS (shared across waves, staged straight through — no reg buffer);
// B-fragments (k[b,:]*qa) built in-register from L2 loads; bias fragment
// preloaded once. __launch_bounds__(256,3) pins the register budget high
// enough (~170) that nothing spills (R7's 73 MB scratch traffic came from
// the compiler capping at 68 VGPRs and spilling the reg caches).
// ---------------------------------------------------------------------------
__global__ __launch_bounds__(256, 3)
void score_kernel(const float* __restrict__ qh,
                  const float* __restrict__ kh,
                  const unsigned short* __restrict__ vh,
                  const float* __restrict__ cbias,
                  float* __restrict__ fused) {
  __shared__ __align__(16) unsigned short Vs[128 * 72];

  const int bid = blockIdx.x;  // (batch*128 + a)*2 + bh
  const int bh = bid & 1;
  const int ab = bid >> 1;
  const int batch = ab >> 7;
  const int a = ab & 127;
  const int tid = threadIdx.x;
  const int w = tid >> 6;
  const int lane = tid & 63;
  const int quad = lane >> 4;
  const int n15 = lane & 15;
  const int col8 = (tid & 7) * 8;
  const int bglob = bh * 64 + w * 16 + n15;

  // preload bias fragment (head-invariant coords) into registers
  const float* __restrict__ bp = cbias + (size_t)ab * 16384;
  f32x4 biasReg[8];
#pragma unroll
  for (int ic = 0; ic < 8; ++ic)
    biasReg[ic] = *(const f32x4*)&bp[bglob * 128 + ic * 16 + quad * 4];

  for (int h = 0; h < 8; ++h) {
    const int i = batch * 8 + h;
    const uint4* __restrict__ vb4 = (const uint4*)(vh + (size_t)i * 8192);
    const float* __restrict__ kr = kh + (size_t)i * 8192 + bglob * 64;
    const float* __restrict__ qa = qh + ((size_t)i * 128 + a) * 64;

    // B-frag source loads (issue early; long-latency globals)
    f32x4 k0 = *(const f32x4*)&kr[quad * 8];
    f32x4 k1 = *(const f32x4*)&kr[quad * 8 + 4];
    f32x4 k2 = *(const f32x4*)&kr[32 + quad * 8];
    f32x4 k3 = *(const f32x4*)&kr[32 + quad * 8 + 4];

    // Vs staging straight through (prev iteration's trailing barrier
    // guarantees the region is no longer being read)
#pragma unroll
    for (int j = 0; j < 4; ++j) {
      const int gg = j * 256 + tid;
      *(uint4*)&Vs[(gg >> 3) * 72 + col8] = vb4[gg];
    }

    // multiply by qa and pack to bf16 in-register
    k0 *= *(const f32x4*)&qa[quad * 8];
    k1 *= *(const f32x4*)&qa[quad * 8 + 4];
    k2 *= *(const f32x4*)&qa[32 + quad * 8];
    k3 *= *(const f32x4*)&qa[32 + quad * 8 + 4];
    U4S8 b0, b1;
    b0.u.x = pk_bf16(k0[0], k0[1]); b0.u.y = pk_bf16(k0[2], k0[3]);
    b0.u.z = pk_bf16(k1[0], k1[1]); b0.u.w = pk_bf16(k1[2], k1[3]);
    b1.u.x = pk_bf16(k2[0], k2[1]); b1.u.y = pk_bf16(k2[2], k2[3]);
    b1.u.z = pk_bf16(k3[0], k3[1]); b1.u.w = pk_bf16(k3[2], k3[3]);

    __syncthreads();  // Vs writes visible

    f32x4 acc[8];
#pragma unroll
    for (int ic = 0; ic < 8; ++ic) acc[ic] = (f32x4){0.f, 0.f, 0.f, 0.f};
#pragma unroll
    for (int ic = 0; ic < 8; ++ic) {
      short8 a0 = *(const short8*)&Vs[(ic * 16 + n15) * 72 + quad * 8];
      short8 a1 = *(const short8*)&Vs[(ic * 16 + n15) * 72 + 32 + quad * 8];
      acc[ic] = __builtin_amdgcn_mfma_f32_16x16x32_bf16(a0, b0.s, acc[ic], 0, 0, 0);
      acc[ic] = __builtin_amdgcn_mfma_f32_16x16x32_bf16(a1, b1.s, acc[ic], 0, 0, 0);
    }
    __syncthreads();  // all Vs reads done before next head's staging

    float fsum = 0.f, fmx = -INFINITY;
#pragma unroll
    for (int ic = 0; ic < 8; ++ic) {
      const float v0 = acc[ic][0] + biasReg[ic][0];
      const float v1 = acc[ic][1] + biasReg[ic][1];
      const float v2 = acc[ic][2] + biasReg[ic][2];
      const float v3 = acc[ic][3] + biasReg[ic][3];
      fsum += (v0 + v1) + (v2 + v3);
      fmx = fmaxf(fmx, fmaxf(fmaxf(v0, v1), fmaxf(v2, v3)));  // v_max3
    }
    fsum += __shfl_xor(fsum, 16, 64);
    fmx = fmaxf(fmx, __shfl_xor(fmx, 16, 64));
    fsum += __shfl_xor(fsum, 32, 64);
    fmx = fmaxf(fmx, __shfl_xor(fmx, 32, 64));
    if (quad == 0)
      fused[((size_t)i * 128 + a) * 128 + bglob] = fsum * (1.0f / 128.0f) + fmx;
  }
}

// ---------------------------------------------------------------------------
// Kernel C: softmax over b + attn[i,a,:] = sum_b w[b]*q[i,b,:]  (verified)
// ---------------------------------------------------------------------------
__global__ __launch_bounds__(64)
void softmax_attn_kernel(const float* __restrict__ fused,
                         const float* __restrict__ qh,
                         float* __restrict__ attn) {
  const int bid = blockIdx.x;  // i*128 + a
  const int i = bid >> 7;
  const int a = bid & 127;
  const int lane = threadIdx.x;
  const float* __restrict__ fr = fused + (size_t)bid * 128;
  float f0 = fr[lane], f1 = fr[lane + 64];
  float m = fmaxf(f0, f1);
#pragma unroll
  for (int off = 32; off >= 1; off >>= 1) m = fmaxf(m, __shfl_xor(m, off, 64));
  const float e0 = expf(f0 - m), e1 = expf(f1 - m);
  float s = e0 + e1;
#pragma unroll
  for (int off = 32; off >= 1; off >>= 1) s += __shfl_xor(s, off, 64);
  const float inv = 1.0f / s;
  __shared__ float w[128];
  w[lane] = e0 * inv;
  w[lane + 64] = e1 * inv;
  __syncthreads();
  const float* __restrict__ qp = qh + (size_t)i * 128 * 64 + lane;
  float acc = 0.0f;
#pragma unroll 4
  for (int b = 0; b < 128; b++) acc = fmaf(w[b], qp[b * 64], acc);
  const int batch = i >> 3, head = i & 7;
  attn[((size_t)a * 8 + batch) * 512 + head * 64 + lane] = acc;
}

// ---------------------------------------------------------------------------
// Kernel D: output projection, hi/lo MFMA (verified R7).
// ---------------------------------------------------------------------------
__global__ __launch_bounds__(256)
void outmm_kernel(const float* __restrict__ Xa,
                  const float* __restrict__ W,
                  const float* __restrict__ bias,
                  float* __restrict__ out) {
  __shared__ __align__(16) unsigned short Ah[64 * 72];
  __shared__ __align__(16) unsigned short Al[64 * 72];
  __shared__ __align__(16) unsigned short Bh[64 * 72];
  __shared__ __align__(16) unsigned short Bl[64 * 72];
  const int n0 = blockIdx.x * 64;  // 0..511
  const int m0 = blockIdx.y * 64;
  const int tid = threadIdx.x;
  const int w = tid >> 6, lane = tid & 63;
  const int quad = lane >> 4, n15 = lane & 15;
  const int srow = tid >> 2;
  const int scol = (tid & 3) * 16;

  f32x4 acc[4];
#pragma unroll
  for (int nt = 0; nt < 4; ++nt) acc[nt] = (f32x4){0.f, 0.f, 0.f, 0.f};

  float4 av[4], bv[4];
#pragma unroll
  for (int jj = 0; jj < 4; ++jj) {
    av[jj] = *(const float4*)&Xa[(m0 + srow) * 512 + scol + 4 * jj];
    bv[jj] = *(const float4*)&W[(n0 + srow) * 512 + scol + 4 * jj];
  }

  for (int k0 = 0; k0 < 512; k0 += 64) {
    __syncthreads();
#pragma unroll
    for (int jj = 0; jj < 4; ++jj) {
      ushort4 hh, ll;
      split4(av[jj], hh, ll);
      *(ushort4*)&Ah[srow * 72 + scol + 4 * jj] = hh;
      *(ushort4*)&Al[srow * 72 + scol + 4 * jj] = ll;
      split4(bv[jj], hh, ll);
      *(ushort4*)&Bh[srow * 72 + scol + 4 * jj] = hh;
      *(ushort4*)&Bl[srow * 72 + scol + 4 * jj] = ll;
    }
    __syncthreads();
    if (k0 + 64 < 512) {
#pragma unroll
      for (int jj = 0; jj < 4; ++jj) {
        av[jj] = *(const float4*)&Xa[(m0 + srow) * 512 + k0 + 64 + scol + 4 * jj];
        bv[jj] = *(const float4*)&W[(n0 + srow) * 512 + k0 + 64 + scol + 4 * jj];
      }
    }
#pragma unroll
    for (int kk = 0; kk < 2; ++kk) {
      short8 ah = *(const short8*)&Ah[(w * 16 + n15) * 72 + kk * 32 + quad * 8];
      short8 al = *(const short8*)&Al[(w * 16 + n15) * 72 + kk * 32 + quad * 8];
#pragma unroll
      for (int nt = 0; nt < 4; ++nt) {
        short8 bh = *(const short8*)&Bh[(nt * 16 + n15) * 72 + kk * 32 + quad * 8];
        short8 bl = *(const short8*)&Bl[(nt * 16 + n15) * 72 + kk * 32 + quad * 8];
        acc[nt] = __builtin_amdgcn_mfma_f32_16x16x32_bf16(ah, bh, acc[nt], 0, 0, 0);
        acc[nt] = __builtin_amdgcn_mfma_f32_16x16x32_bf16(ah, bl, acc[nt], 0, 0, 0);
        acc[nt] = __builtin_amdgcn_mfma_f32_16x16x32_bf16(al, bh, acc[nt], 0, 0, 0);
      }
    }
  }

#pragma unroll
  for (int nt = 0; nt < 4; ++nt) {
    const int j = n0 + nt * 16 + n15;
    const float bj = bias[j];
#pragma unroll
    for (int r = 0; r < 4; ++r) {
      const int row = m0 + w * 16 + quad * 4 + r;
      out[(size_t)row * 512 + j] = acc[nt][r] + bj;
    }
  }
}

extern "C" void kernel_launch(void* const* d_in, const int* in_sizes, int n_in,
                              void* d_out, int out_size, void* d_ws,
                              size_t ws_size, hipStream_t stream) {
  const float* query = (const float*)d_in[0];
  const float* key   = (const float*)d_in[1];
  const float* value = (const float*)d_in[2];
  const float* cbias = (const float*)d_in[3];
  const float* W     = (const float*)d_in[4];
  const float* pb    = (const float*)d_in[5];
  const float* out_w = (const float*)d_in[6];
  const float* out_b = (const float*)d_in[7];
  float* out = (float*)d_out;

  float* ws = (float*)d_ws;
  float* qh = ws;                                        // 524288 f
  float* kh = ws + 524288;                               // 524288 f
  unsigned short* vh = (unsigned short*)(ws + 1048576);  // 524288 bf16
  float* fusedb = ws + 1048576 + 262144;                 // 1048576 f
  float* attn = fusedb + 1048576;                        // 524288 f

  projmm_kernel<<<dim3(24, 16), 256, 0, stream>>>(query, key, value, W, pb,
                                                  qh, kh, vh);
  score_kernel<<<2048, 256, 0, stream>>>(qh, kh, vh, cbias, fusedb);
  softmax_attn_kernel<<<8192, 64, 0, stream>>>(fusedb, qh, attn);
  outmm_kernel<<<dim3(8, 16), 256, 0, stream>>>(attn, out_w, out_b, out);
}

// Round 9
// 185.554 us; speedup vs baseline: 1.3539x; 1.0887x over previous
//
#include <hip/hip_runtime.h>
#include <math.h>

#define SCALING 0.125f

typedef __attribute__((ext_vector_type(8))) short short8;
typedef __attribute__((ext_vector_type(4))) float f32x4;

// round-to-nearest-even fp32 -> bf16
static __device__ __forceinline__ unsigned short bf16r(float x) {
  unsigned int u = __float_as_uint(x);
  u += 0x7fffu + ((u >> 16) & 1u);
  return (unsigned short)(u >> 16);
}
static __device__ __forceinline__ float bf16f(unsigned short h) {
  return __uint_as_float(((unsigned int)h) << 16);
}
// pack two fp32 -> bf16x2 via v_perm_b32 merge
static __device__ __forceinline__ unsigned int pk_bf16(float lo, float hi) {
  unsigned int ua = __float_as_uint(lo);
  unsigned int ub = __float_as_uint(hi);
  ua += 0x7fffu + ((ua >> 16) & 1u);
  ub += 0x7fffu + ((ub >> 16) & 1u);
  return __builtin_amdgcn_perm(ub, ua, 0x07060302u);
}
// fp32x4 -> bf16 hi + residual lo
static __device__ __forceinline__ void split4(float4 x, ushort4& h, ushort4& l) {
  h.x = bf16r(x.x); l.x = bf16r(x.x - bf16f(h.x));
  h.y = bf16r(x.y); l.y = bf16r(x.y - bf16f(h.y));
  h.z = bf16r(x.z); l.z = bf16r(x.z - bf16f(h.z));
  h.w = bf16r(x.w); l.w = bf16r(x.w - bf16f(h.w));
}
union U4S8 { uint4 u; short8 s; };

// ---------------------------------------------------------------------------
// Kernel A: in-projection GEMM, hi/lo bf16 MFMA (verified R7/R8).
// ---------------------------------------------------------------------------
__global__ __launch_bounds__(256)
void projmm_kernel(const float* __restrict__ query,
                   const float* __restrict__ key,
                   const float* __restrict__ value,
                   const float* __restrict__ W,
                   const float* __restrict__ bias,
                   float* __restrict__ qh, float* __restrict__ kh,
                   unsigned short* __restrict__ vh) {
  __shared__ __align__(16) unsigned short Ah[64 * 72];
  __shared__ __align__(16) unsigned short Al[64 * 72];
  __shared__ __align__(16) unsigned short Bh[64 * 72];
  __shared__ __align__(16) unsigned short Bl[64 * 72];
  const int n0 = blockIdx.x * 64;  // 0..1535
  const int g = n0 >> 9;           // 0=q,1=k,2=v
  const float* __restrict__ X = (g == 0) ? query : (g == 1) ? key : value;
  const int m0 = blockIdx.y * 64;
  const int tid = threadIdx.x;
  const int w = tid >> 6, lane = tid & 63;
  const int quad = lane >> 4, n15 = lane & 15;
  const int srow = tid >> 2;        // 0..63
  const int scol = (tid & 3) * 16;  // 0,16,32,48

  f32x4 acc[4];
#pragma unroll
  for (int nt = 0; nt < 4; ++nt) acc[nt] = (f32x4){0.f, 0.f, 0.f, 0.f};

  float4 av[4], bv[4];
#pragma unroll
  for (int jj = 0; jj < 4; ++jj) {
    av[jj] = *(const float4*)&X[(m0 + srow) * 512 + scol + 4 * jj];
    bv[jj] = *(const float4*)&W[(n0 + srow) * 512 + scol + 4 * jj];
  }

  for (int k0 = 0; k0 < 512; k0 += 64) {
    __syncthreads();
#pragma unroll
    for (int jj = 0; jj < 4; ++jj) {
      ushort4 hh, ll;
      split4(av[jj], hh, ll);
      *(ushort4*)&Ah[srow * 72 + scol + 4 * jj] = hh;
      *(ushort4*)&Al[srow * 72 + scol + 4 * jj] = ll;
      split4(bv[jj], hh, ll);
      *(ushort4*)&Bh[srow * 72 + scol + 4 * jj] = hh;
      *(ushort4*)&Bl[srow * 72 + scol + 4 * jj] = ll;
    }
    __syncthreads();
    if (k0 + 64 < 512) {
#pragma unroll
      for (int jj = 0; jj < 4; ++jj) {
        av[jj] = *(const float4*)&X[(m0 + srow) * 512 + k0 + 64 + scol + 4 * jj];
        bv[jj] = *(const float4*)&W[(n0 + srow) * 512 + k0 + 64 + scol + 4 * jj];
      }
    }
#pragma unroll
    for (int kk = 0; kk < 2; ++kk) {
      short8 ah = *(const short8*)&Ah[(w * 16 + n15) * 72 + kk * 32 + quad * 8];
      short8 al = *(const short8*)&Al[(w * 16 + n15) * 72 + kk * 32 + quad * 8];
#pragma unroll
      for (int nt = 0; nt < 4; ++nt) {
        short8 bh = *(const short8*)&Bh[(nt * 16 + n15) * 72 + kk * 32 + quad * 8];
        short8 bl = *(const short8*)&Bl[(nt * 16 + n15) * 72 + kk * 32 + quad * 8];
        acc[nt] = __builtin_amdgcn_mfma_f32_16x16x32_bf16(ah, bh, acc[nt], 0, 0, 0);
        acc[nt] = __builtin_amdgcn_mfma_f32_16x16x32_bf16(ah, bl, acc[nt], 0, 0, 0);
        acc[nt] = __builtin_amdgcn_mfma_f32_16x16x32_bf16(al, bh, acc[nt], 0, 0, 0);
      }
    }
  }

#pragma unroll
  for (int nt = 0; nt < 4; ++nt) {
    const int j = n0 + nt * 16 + n15;
    const int jj = j & 511;
    const int head = jj >> 6;
    const int hd = jj & 63;
    const float bj = bias[j];
#pragma unroll
    for (int r = 0; r < 4; ++r) {
      const int row = m0 + w * 16 + quad * 4 + r;
      const int t = row >> 3;
      const int batch = row & 7;
      const int i = batch * 8 + head;
      const int idx = ((i << 7) + t) * 64 + hd;
      const float val = acc[nt][r] + bj;
      if (g == 0)      qh[idx] = val * SCALING;
      else if (g == 1) kh[idx] = val;
      else             vh[idx] = bf16r(val);
    }
  }
}

// ---------------------------------------------------------------------------
// Kernel B: one block per (batch,a); double-buffered head loop, ONE barrier
// per head. At head h: issue head h+1's coalesced global loads, MFMA from
// buffer[h&1] while they fly, pack+store into buffer[1-(h&1)], reg-bias
// epilogue, barrier. Wave strips are 32 b wide (R2-verified mapping) to
// halve LDS A-read traffic. biasReg preloaded once (head-invariant).
// __launch_bounds__(256,2): ~256-VGPR cap vs ~220 demand -> no spill.
// ---------------------------------------------------------------------------
__global__ __launch_bounds__(256, 2)
void score_kernel(const float* __restrict__ qh,
                  const float* __restrict__ kh,
                  const unsigned short* __restrict__ vh,
                  const float* __restrict__ cbias,
                  float* __restrict__ fused) {
  __shared__ __align__(16) unsigned short Ks[2][128 * 72];
  __shared__ __align__(16) unsigned short Vs[2][128 * 72];

  const int ab = blockIdx.x;  // batch*128 + a
  const int batch = ab >> 7;
  const int a = ab & 127;
  const int tid = threadIdx.x;
  const int w = tid >> 6;
  const int lane = tid & 63;
  const int quad = lane >> 4;
  const int n15 = lane & 15;
  const int col8 = (tid & 7) * 8;

  // bias fragment preload (head-invariant coords; verified R2/R4 mapping)
  const float* __restrict__ bp = cbias + (size_t)ab * 16384;
  f32x4 biasReg[8][2];
#pragma unroll
  for (int ic = 0; ic < 8; ++ic)
#pragma unroll
    for (int jb = 0; jb < 2; ++jb) {
      const int b = w * 32 + jb * 16 + n15;
      biasReg[ic][jb] = *(const f32x4*)&bp[b * 128 + ic * 16 + quad * 4];
    }

  // ---- prologue: stage head 0 into buffer 0 ----
  {
    const int i = batch * 8;
    const float* __restrict__ kb = kh + (size_t)i * 8192;
    const uint4* __restrict__ vb4 = (const uint4*)(vh + (size_t)i * 8192);
    const float* __restrict__ qa = qh + ((size_t)i * 128 + a) * 64;
    f32x4 q0 = *(const f32x4*)&qa[col8];
    f32x4 q1 = *(const f32x4*)&qa[col8 + 4];
#pragma unroll
    for (int j = 0; j < 4; ++j) {
      const int gg = j * 256 + tid;
      const int row = gg >> 3;
      *(uint4*)&Vs[0][row * 72 + col8] = vb4[gg];
      f32x4 k0 = *(const f32x4*)&kb[8 * gg];
      f32x4 k1 = *(const f32x4*)&kb[8 * gg + 4];
      k0 *= q0;
      k1 *= q1;
      uint4 pk;
      pk.x = pk_bf16(k0[0], k0[1]); pk.y = pk_bf16(k0[2], k0[3]);
      pk.z = pk_bf16(k1[0], k1[1]); pk.w = pk_bf16(k1[2], k1[3]);
      *(uint4*)&Ks[0][row * 72 + col8] = pk;
    }
  }
  __syncthreads();

  for (int h = 0; h < 8; ++h) {
    const int buf = h & 1;
    const int i = batch * 8 + h;

    // ---- issue next head's global loads (coalesced; in flight during MFMA)
    uint4 vreg[4];
    f32x4 kreg[4][2];
    f32x4 qn0, qn1;
    if (h < 7) {
      const int in = i + 1;
      const float* __restrict__ kb = kh + (size_t)in * 8192;
      const uint4* __restrict__ vb4 = (const uint4*)(vh + (size_t)in * 8192);
      const float* __restrict__ qa = qh + ((size_t)in * 128 + a) * 64;
      qn0 = *(const f32x4*)&qa[col8];
      qn1 = *(const f32x4*)&qa[col8 + 4];
#pragma unroll
      for (int j = 0; j < 4; ++j) {
        const int gg = j * 256 + tid;
        vreg[j] = vb4[gg];
        kreg[j][0] = *(const f32x4*)&kb[8 * gg];
        kreg[j][1] = *(const f32x4*)&kb[8 * gg + 4];
      }
    }

    // ---- B-fragments from Ks[buf] (R2-verified 32-wide strip mapping)
    short8 bf[2][2];
#pragma unroll
    for (int jb = 0; jb < 2; ++jb)
#pragma unroll
      for (int kk = 0; kk < 2; ++kk)
        bf[jb][kk] = *(const short8*)&Ks[buf][(w * 32 + jb * 16 + n15) * 72 +
                                             kk * 32 + quad * 8];

    // ---- MFMA: S^T[c,b] (global loads for h+1 still in flight)
    f32x4 acc[8][2];
#pragma unroll
    for (int ic = 0; ic < 8; ++ic)
#pragma unroll
      for (int jb = 0; jb < 2; ++jb) acc[ic][jb] = (f32x4){0.f, 0.f, 0.f, 0.f};
#pragma unroll
    for (int ic = 0; ic < 8; ++ic) {
      short8 a0 = *(const short8*)&Vs[buf][(ic * 16 + n15) * 72 + quad * 8];
      short8 a1 = *(const short8*)&Vs[buf][(ic * 16 + n15) * 72 + 32 + quad * 8];
      acc[ic][0] = __builtin_amdgcn_mfma_f32_16x16x32_bf16(a0, bf[0][0], acc[ic][0], 0, 0, 0);
      acc[ic][0] = __builtin_amdgcn_mfma_f32_16x16x32_bf16(a1, bf[0][1], acc[ic][0], 0, 0, 0);
      acc[ic][1] = __builtin_amdgcn_mfma_f32_16x16x32_bf16(a0, bf[1][0], acc[ic][1], 0, 0, 0);
      acc[ic][1] = __builtin_amdgcn_mfma_f32_16x16x32_bf16(a1, bf[1][1], acc[ic][1], 0, 0, 0);
    }

    // ---- pack + store next head's staging into the other buffer
    if (h < 7) {
      const int nb = buf ^ 1;
#pragma unroll
      for (int j = 0; j < 4; ++j) {
        const int gg = j * 256 + tid;
        const int row = gg >> 3;
        *(uint4*)&Vs[nb][row * 72 + col8] = vreg[j];
        kreg[j][0] *= qn0;
        kreg[j][1] *= qn1;
        uint4 pk;
        pk.x = pk_bf16(kreg[j][0][0], kreg[j][0][1]);
        pk.y = pk_bf16(kreg[j][0][2], kreg[j][0][3]);
        pk.z = pk_bf16(kreg[j][1][0], kreg[j][1][1]);
        pk.w = pk_bf16(kreg[j][1][2], kreg[j][1][3]);
        *(uint4*)&Ks[nb][row * 72 + col8] = pk;
      }
    }

    // ---- epilogue: bias add (registers) + mean/max over c, cross-quad
    float fsum[2] = {0.f, 0.f};
    float fmx[2] = {-INFINITY, -INFINITY};
#pragma unroll
    for (int ic = 0; ic < 8; ++ic)
#pragma unroll
      for (int jb = 0; jb < 2; ++jb) {
        const float v0 = acc[ic][jb][0] + biasReg[ic][jb][0];
        const float v1 = acc[ic][jb][1] + biasReg[ic][jb][1];
        const float v2 = acc[ic][jb][2] + biasReg[ic][jb][2];
        const float v3 = acc[ic][jb][3] + biasReg[ic][jb][3];
        fsum[jb] += (v0 + v1) + (v2 + v3);
        fmx[jb] = fmaxf(fmx[jb], fmaxf(fmaxf(v0, v1), fmaxf(v2, v3)));
      }
#pragma unroll
    for (int off = 16; off <= 32; off <<= 1) {
#pragma unroll
      for (int jb = 0; jb < 2; ++jb) {
        fsum[jb] += __shfl_xor(fsum[jb], off, 64);
        fmx[jb] = fmaxf(fmx[jb], __shfl_xor(fmx[jb], off, 64));
      }
    }
    if (quad == 0) {
      float* fo = fused + ((size_t)i * 128 + a) * 128 + w * 32;
      fo[n15] = fsum[0] * (1.0f / 128.0f) + fmx[0];
      fo[16 + n15] = fsum[1] * (1.0f / 128.0f) + fmx[1];
    }

    __syncthreads();  // h's reads of buf done; h's writes to buf^1 visible
  }
}

// ---------------------------------------------------------------------------
// Kernel C: softmax over b + attn[i,a,:] = sum_b w[b]*q[i,b,:]  (verified)
// ---------------------------------------------------------------------------
__global__ __launch_bounds__(64)
void softmax_attn_kernel(const float* __restrict__ fused,
                         const float* __restrict__ qh,
                         float* __restrict__ attn) {
  const int bid = blockIdx.x;  // i*128 + a
  const int i = bid >> 7;
  const int a = bid & 127;
  const int lane = threadIdx.x;
  const float* __restrict__ fr = fused + (size_t)bid * 128;
  float f0 = fr[lane], f1 = fr[lane + 64];
  float m = fmaxf(f0, f1);
#pragma unroll
  for (int off = 32; off >= 1; off >>= 1) m = fmaxf(m, __shfl_xor(m, off, 64));
  const float e0 = expf(f0 - m), e1 = expf(f1 - m);
  float s = e0 + e1;
#pragma unroll
  for (int off = 32; off >= 1; off >>= 1) s += __shfl_xor(s, off, 64);
  const float inv = 1.0f / s;
  __shared__ float w[128];
  w[lane] = e0 * inv;
  w[lane + 64] = e1 * inv;
  __syncthreads();
  const float* __restrict__ qp = qh + (size_t)i * 128 * 64 + lane;
  float acc = 0.0f;
#pragma unroll 4
  for (int b = 0; b < 128; b++) acc = fmaf(w[b], qp[b * 64], acc);
  const int batch = i >> 3, head = i & 7;
  attn[((size_t)a * 8 + batch) * 512 + head * 64 + lane] = acc;
}

// ---------------------------------------------------------------------------
// Kernel D: output projection, hi/lo MFMA (verified R7/R8).
// ---------------------------------------------------------------------------
__global__ __launch_bounds__(256)
void outmm_kernel(const float* __restrict__ Xa,
                  const float* __restrict__ W,
                  const float* __restrict__ bias,
                  float* __restrict__ out) {
  __shared__ __align__(16) unsigned short Ah[64 * 72];
  __shared__ __align__(16) unsigned short Al[64 * 72];
  __shared__ __align__(16) unsigned short Bh[64 * 72];
  __shared__ __align__(16) unsigned short Bl[64 * 72];
  const int n0 = blockIdx.x * 64;  // 0..511
  const int m0 = blockIdx.y * 64;
  const int tid = threadIdx.x;
  const int w = tid >> 6, lane = tid & 63;
  const int quad = lane >> 4, n15 = lane & 15;
  const int srow = tid >> 2;
  const int scol = (tid & 3) * 16;

  f32x4 acc[4];
#pragma unroll
  for (int nt = 0; nt < 4; ++nt) acc[nt] = (f32x4){0.f, 0.f, 0.f, 0.f};

  float4 av[4], bv[4];
#pragma unroll
  for (int jj = 0; jj < 4; ++jj) {
    av[jj] = *(const float4*)&Xa[(m0 + srow) * 512 + scol + 4 * jj];
    bv[jj] = *(const float4*)&W[(n0 + srow) * 512 + scol + 4 * jj];
  }

  for (int k0 = 0; k0 < 512; k0 += 64) {
    __syncthreads();
#pragma unroll
    for (int jj = 0; jj < 4; ++jj) {
      ushort4 hh, ll;
      split4(av[jj], hh, ll);
      *(ushort4*)&Ah[srow * 72 + scol + 4 * jj] = hh;
      *(ushort4*)&Al[srow * 72 + scol + 4 * jj] = ll;
      split4(bv[jj], hh, ll);
      *(ushort4*)&Bh[srow * 72 + scol + 4 * jj] = hh;
      *(ushort4*)&Bl[srow * 72 + scol + 4 * jj] = ll;
    }
    __syncthreads();
    if (k0 + 64 < 512) {
#pragma unroll
      for (int jj = 0; jj < 4; ++jj) {
        av[jj] = *(const float4*)&Xa[(m0 + srow) * 512 + k0 + 64 + scol + 4 * jj];
        bv[jj] = *(const float4*)&W[(n0 + srow) * 512 + k0 + 64 + scol + 4 * jj];
      }
    }
#pragma unroll
    for (int kk = 0; kk < 2; ++kk) {
      short8 ah = *(const short8*)&Ah[(w * 16 + n15) * 72 + kk * 32 + quad * 8];
      short8 al = *(const short8*)&Al[(w * 16 + n15) * 72 + kk * 32 + quad * 8];
#pragma unroll
      for (int nt = 0; nt < 4; ++nt) {
        short8 bh = *(const short8*)&Bh[(nt * 16 + n15) * 72 + kk * 32 + quad * 8];
        short8 bl = *(const short8*)&Bl[(nt * 16 + n15) * 72 + kk * 32 + quad * 8];
        acc[nt] = __builtin_amdgcn_mfma_f32_16x16x32_bf16(ah, bh, acc[nt], 0, 0, 0);
        acc[nt] = __builtin_amdgcn_mfma_f32_16x16x32_bf16(ah, bl, acc[nt], 0, 0, 0);
        acc[nt] = __builtin_amdgcn_mfma_f32_16x16x32_bf16(al, bh, acc[nt], 0, 0, 0);
      }
    }
  }

#pragma unroll
  for (int nt = 0; nt < 4; ++nt) {
    const int j = n0 + nt * 16 + n15;
    const float bj = bias[j];
#pragma unroll
    for (int r = 0; r < 4; ++r) {
      const int row = m0 + w * 16 + quad * 4 + r;
      out[(size_t)row * 512 + j] = acc[nt][r] + bj;
    }
  }
}

extern "C" void kernel_launch(void* const* d_in, const int* in_sizes, int n_in,
                              void* d_out, int out_size, void* d_ws,
                              size_t ws_size, hipStream_t stream) {
  const float* query = (const float*)d_in[0];
  const float* key   = (const float*)d_in[1];
  const float* value = (const float*)d_in[2];
  const float* cbias = (const float*)d_in[3];
  const float* W     = (const float*)d_in[4];
  const float* pb    = (const float*)d_in[5];
  const float* out_w = (const float*)d_in[6];
  const float* out_b = (const float*)d_in[7];
  float* out = (float*)d_out;

  float* ws = (float*)d_ws;
  float* qh = ws;                                        // 524288 f
  float* kh = ws + 524288;                               // 524288 f
  unsigned short* vh = (unsigned short*)(ws + 1048576);  // 524288 bf16
  float* fusedb = ws + 1048576 + 262144;                 // 1048576 f
  float* attn = fusedb + 1048576;                        // 524288 f

  projmm_kernel<<<dim3(24, 16), 256, 0, stream>>>(query, key, value, W, pb,
                                                  qh, kh, vh);
  score_kernel<<<1024, 256, 0, stream>>>(qh, kh, vh, cbias, fusedb);
  softmax_attn_kernel<<<8192, 64, 0, stream>>>(fusedb, qh, attn);
  outmm_kernel<<<dim3(8, 16), 256, 0, stream>>>(attn, out_w, out_b, out);
}

// Round 10
// 185.263 us; speedup vs baseline: 1.3561x; 1.0016x over previous
//
#include <hip/hip_runtime.h>
#include <math.h>

#define SCALING 0.125f

typedef __attribute__((ext_vector_type(8))) short short8;
typedef __attribute__((ext_vector_type(4))) float f32x4;

// round-to-nearest-even fp32 -> bf16
static __device__ __forceinline__ unsigned short bf16r(float x) {
  unsigned int u = __float_as_uint(x);
  u += 0x7fffu + ((u >> 16) & 1u);
  return (unsigned short)(u >> 16);
}
static __device__ __forceinline__ float bf16f(unsigned short h) {
  return __uint_as_float(((unsigned int)h) << 16);
}
// pack two fp32 -> bf16x2 via v_perm_b32 merge
static __device__ __forceinline__ unsigned int pk_bf16(float lo, float hi) {
  unsigned int ua = __float_as_uint(lo);
  unsigned int ub = __float_as_uint(hi);
  ua += 0x7fffu + ((ua >> 16) & 1u);
  ub += 0x7fffu + ((ub >> 16) & 1u);
  return __builtin_amdgcn_perm(ub, ua, 0x07060302u);
}
// fp32x4 -> bf16 hi + residual lo
static __device__ __forceinline__ void split4(float4 x, ushort4& h, ushort4& l) {
  h.x = bf16r(x.x); l.x = bf16r(x.x - bf16f(h.x));
  h.y = bf16r(x.y); l.y = bf16r(x.y - bf16f(h.y));
  h.z = bf16r(x.z); l.z = bf16r(x.z - bf16f(h.z));
  h.w = bf16r(x.w); l.w = bf16r(x.w - bf16f(h.w));
}
union U4S8 { uint4 u; short8 s; };

// ---------------------------------------------------------------------------
// Kernel A: in-projection GEMM, hi/lo bf16 MFMA (verified R7/R8/R9).
// ---------------------------------------------------------------------------
__global__ __launch_bounds__(256)
void projmm_kernel(const float* __restrict__ query,
                   const float* __restrict__ key,
                   const float* __restrict__ value,
                   const float* __restrict__ W,
                   const float* __restrict__ bias,
                   float* __restrict__ qh, float* __restrict__ kh,
                   unsigned short* __restrict__ vh) {
  __shared__ __align__(16) unsigned short Ah[64 * 72];
  __shared__ __align__(16) unsigned short Al[64 * 72];
  __shared__ __align__(16) unsigned short Bh[64 * 72];
  __shared__ __align__(16) unsigned short Bl[64 * 72];
  const int n0 = blockIdx.x * 64;  // 0..1535
  const int g = n0 >> 9;           // 0=q,1=k,2=v
  const float* __restrict__ X = (g == 0) ? query : (g == 1) ? key : value;
  const int m0 = blockIdx.y * 64;
  const int tid = threadIdx.x;
  const int w = tid >> 6, lane = tid & 63;
  const int quad = lane >> 4, n15 = lane & 15;
  const int srow = tid >> 2;        // 0..63
  const int scol = (tid & 3) * 16;  // 0,16,32,48

  f32x4 acc[4];
#pragma unroll
  for (int nt = 0; nt < 4; ++nt) acc[nt] = (f32x4){0.f, 0.f, 0.f, 0.f};

  float4 av[4], bv[4];
#pragma unroll
  for (int jj = 0; jj < 4; ++jj) {
    av[jj] = *(const float4*)&X[(m0 + srow) * 512 + scol + 4 * jj];
    bv[jj] = *(const float4*)&W[(n0 + srow) * 512 + scol + 4 * jj];
  }

  for (int k0 = 0; k0 < 512; k0 += 64) {
    __syncthreads();
#pragma unroll
    for (int jj = 0; jj < 4; ++jj) {
      ushort4 hh, ll;
      split4(av[jj], hh, ll);
      *(ushort4*)&Ah[srow * 72 + scol + 4 * jj] = hh;
      *(ushort4*)&Al[srow * 72 + scol + 4 * jj] = ll;
      split4(bv[jj], hh, ll);
      *(ushort4*)&Bh[srow * 72 + scol + 4 * jj] = hh;
      *(ushort4*)&Bl[srow * 72 + scol + 4 * jj] = ll;
    }
    __syncthreads();
    if (k0 + 64 < 512) {
#pragma unroll
      for (int jj = 0; jj < 4; ++jj) {
        av[jj] = *(const float4*)&X[(m0 + srow) * 512 + k0 + 64 + scol + 4 * jj];
        bv[jj] = *(const float4*)&W[(n0 + srow) * 512 + k0 + 64 + scol + 4 * jj];
      }
    }
#pragma unroll
    for (int kk = 0; kk < 2; ++kk) {
      short8 ah = *(const short8*)&Ah[(w * 16 + n15) * 72 + kk * 32 + quad * 8];
      short8 al = *(const short8*)&Al[(w * 16 + n15) * 72 + kk * 32 + quad * 8];
#pragma unroll
      for (int nt = 0; nt < 4; ++nt) {
        short8 bh = *(const short8*)&Bh[(nt * 16 + n15) * 72 + kk * 32 + quad * 8];
        short8 bl = *(const short8*)&Bl[(nt * 16 + n15) * 72 + kk * 32 + quad * 8];
        acc[nt] = __builtin_amdgcn_mfma_f32_16x16x32_bf16(ah, bh, acc[nt], 0, 0, 0);
        acc[nt] = __builtin_amdgcn_mfma_f32_16x16x32_bf16(ah, bl, acc[nt], 0, 0, 0);
        acc[nt] = __builtin_amdgcn_mfma_f32_16x16x32_bf16(al, bh, acc[nt], 0, 0, 0);
      }
    }
  }

#pragma unroll
  for (int nt = 0; nt < 4; ++nt) {
    const int j = n0 + nt * 16 + n15;
    const int jj = j & 511;
    const int head = jj >> 6;
    const int hd = jj & 63;
    const float bj = bias[j];
#pragma unroll
    for (int r = 0; r < 4; ++r) {
      const int row = m0 + w * 16 + quad * 4 + r;
      const int t = row >> 3;
      const int batch = row & 7;
      const int i = batch * 8 + head;
      const int idx = ((i << 7) + t) * 64 + hd;
      const float val = acc[nt][r] + bj;
      if (g == 0)      qh[idx] = val * SCALING;
      else if (g == 1) kh[idx] = val;
      else             vh[idx] = bf16r(val);
    }
  }
}

// ---------------------------------------------------------------------------
// Kernel B: one block per (batch,a). R9-verified double-buffered head loop
// (one barrier/head, biasReg preload, 32-wide b-strips) + FUSED tail:
// fused rows kept in LDS (rowS), then per-wave softmax (2 heads/wave,
// verbatim verified math) + attn bmm against L2-hot qh. Removes the
// softmax dispatch and the fusedb HBM round-trip.
// ---------------------------------------------------------------------------
__global__ __launch_bounds__(256, 2)
void score_kernel(const float* __restrict__ qh,
                  const float* __restrict__ kh,
                  const unsigned short* __restrict__ vh,
                  const float* __restrict__ cbias,
                  float* __restrict__ attn) {
  __shared__ __align__(16) unsigned short Ks[2][128 * 72];
  __shared__ __align__(16) unsigned short Vs[2][128 * 72];
  __shared__ float rowS[8 * 128];  // fused rows, then softmax weights

  const int ab = blockIdx.x;  // batch*128 + a
  const int batch = ab >> 7;
  const int a = ab & 127;
  const int tid = threadIdx.x;
  const int w = tid >> 6;
  const int lane = tid & 63;
  const int quad = lane >> 4;
  const int n15 = lane & 15;
  const int col8 = (tid & 7) * 8;

  // bias fragment preload (head-invariant coords; verified mapping)
  const float* __restrict__ bp = cbias + (size_t)ab * 16384;
  f32x4 biasReg[8][2];
#pragma unroll
  for (int ic = 0; ic < 8; ++ic)
#pragma unroll
    for (int jb = 0; jb < 2; ++jb) {
      const int b = w * 32 + jb * 16 + n15;
      biasReg[ic][jb] = *(const f32x4*)&bp[b * 128 + ic * 16 + quad * 4];
    }

  // ---- prologue: stage head 0 into buffer 0 ----
  {
    const int i = batch * 8;
    const float* __restrict__ kb = kh + (size_t)i * 8192;
    const uint4* __restrict__ vb4 = (const uint4*)(vh + (size_t)i * 8192);
    const float* __restrict__ qa = qh + ((size_t)i * 128 + a) * 64;
    f32x4 q0 = *(const f32x4*)&qa[col8];
    f32x4 q1 = *(const f32x4*)&qa[col8 + 4];
#pragma unroll
    for (int j = 0; j < 4; ++j) {
      const int gg = j * 256 + tid;
      const int row = gg >> 3;
      *(uint4*)&Vs[0][row * 72 + col8] = vb4[gg];
      f32x4 k0 = *(const f32x4*)&kb[8 * gg];
      f32x4 k1 = *(const f32x4*)&kb[8 * gg + 4];
      k0 *= q0;
      k1 *= q1;
      uint4 pk;
      pk.x = pk_bf16(k0[0], k0[1]); pk.y = pk_bf16(k0[2], k0[3]);
      pk.z = pk_bf16(k1[0], k1[1]); pk.w = pk_bf16(k1[2], k1[3]);
      *(uint4*)&Ks[0][row * 72 + col8] = pk;
    }
  }
  __syncthreads();

  for (int h = 0; h < 8; ++h) {
    const int buf = h & 1;
    const int i = batch * 8 + h;

    // ---- issue next head's global loads (in flight during MFMA)
    uint4 vreg[4];
    f32x4 kreg[4][2];
    f32x4 qn0, qn1;
    if (h < 7) {
      const int in = i + 1;
      const float* __restrict__ kb = kh + (size_t)in * 8192;
      const uint4* __restrict__ vb4 = (const uint4*)(vh + (size_t)in * 8192);
      const float* __restrict__ qa = qh + ((size_t)in * 128 + a) * 64;
      qn0 = *(const f32x4*)&qa[col8];
      qn1 = *(const f32x4*)&qa[col8 + 4];
#pragma unroll
      for (int j = 0; j < 4; ++j) {
        const int gg = j * 256 + tid;
        vreg[j] = vb4[gg];
        kreg[j][0] = *(const f32x4*)&kb[8 * gg];
        kreg[j][1] = *(const f32x4*)&kb[8 * gg + 4];
      }
    }

    // ---- B-fragments from Ks[buf]
    short8 bf[2][2];
#pragma unroll
    for (int jb = 0; jb < 2; ++jb)
#pragma unroll
      for (int kk = 0; kk < 2; ++kk)
        bf[jb][kk] = *(const short8*)&Ks[buf][(w * 32 + jb * 16 + n15) * 72 +
                                             kk * 32 + quad * 8];

    // ---- MFMA: S^T[c,b]
    f32x4 acc[8][2];
#pragma unroll
    for (int ic = 0; ic < 8; ++ic)
#pragma unroll
      for (int jb = 0; jb < 2; ++jb) acc[ic][jb] = (f32x4){0.f, 0.f, 0.f, 0.f};
#pragma unroll
    for (int ic = 0; ic < 8; ++ic) {
      short8 a0 = *(const short8*)&Vs[buf][(ic * 16 + n15) * 72 + quad * 8];
      short8 a1 = *(const short8*)&Vs[buf][(ic * 16 + n15) * 72 + 32 + quad * 8];
      acc[ic][0] = __builtin_amdgcn_mfma_f32_16x16x32_bf16(a0, bf[0][0], acc[ic][0], 0, 0, 0);
      acc[ic][0] = __builtin_amdgcn_mfma_f32_16x16x32_bf16(a1, bf[0][1], acc[ic][0], 0, 0, 0);
      acc[ic][1] = __builtin_amdgcn_mfma_f32_16x16x32_bf16(a0, bf[1][0], acc[ic][1], 0, 0, 0);
      acc[ic][1] = __builtin_amdgcn_mfma_f32_16x16x32_bf16(a1, bf[1][1], acc[ic][1], 0, 0, 0);
    }

    // ---- pack + store next head's staging into the other buffer
    if (h < 7) {
      const int nb = buf ^ 1;
#pragma unroll
      for (int j = 0; j < 4; ++j) {
        const int gg = j * 256 + tid;
        const int row = gg >> 3;
        *(uint4*)&Vs[nb][row * 72 + col8] = vreg[j];
        kreg[j][0] *= qn0;
        kreg[j][1] *= qn1;
        uint4 pk;
        pk.x = pk_bf16(kreg[j][0][0], kreg[j][0][1]);
        pk.y = pk_bf16(kreg[j][0][2], kreg[j][0][3]);
        pk.z = pk_bf16(kreg[j][1][0], kreg[j][1][1]);
        pk.w = pk_bf16(kreg[j][1][2], kreg[j][1][3]);
        *(uint4*)&Ks[nb][row * 72 + col8] = pk;
      }
    }

    // ---- epilogue: bias add (registers) + mean/max over c -> rowS (LDS)
    float fsum[2] = {0.f, 0.f};
    float fmx[2] = {-INFINITY, -INFINITY};
#pragma unroll
    for (int ic = 0; ic < 8; ++ic)
#pragma unroll
      for (int jb = 0; jb < 2; ++jb) {
        const float v0 = acc[ic][jb][0] + biasReg[ic][jb][0];
        const float v1 = acc[ic][jb][1] + biasReg[ic][jb][1];
        const float v2 = acc[ic][jb][2] + biasReg[ic][jb][2];
        const float v3 = acc[ic][jb][3] + biasReg[ic][jb][3];
        fsum[jb] += (v0 + v1) + (v2 + v3);
        fmx[jb] = fmaxf(fmx[jb], fmaxf(fmaxf(v0, v1), fmaxf(v2, v3)));
      }
#pragma unroll
    for (int off = 16; off <= 32; off <<= 1) {
#pragma unroll
      for (int jb = 0; jb < 2; ++jb) {
        fsum[jb] += __shfl_xor(fsum[jb], off, 64);
        fmx[jb] = fmaxf(fmx[jb], __shfl_xor(fmx[jb], off, 64));
      }
    }
    if (quad == 0) {
      rowS[h * 128 + w * 32 + n15] = fsum[0] * (1.0f / 128.0f) + fmx[0];
      rowS[h * 128 + w * 32 + 16 + n15] = fsum[1] * (1.0f / 128.0f) + fmx[1];
    }

    __syncthreads();  // h's reads done; h's stores visible; rowS visible
  }

  // ---- fused tail: softmax over b + attn bmm; wave w handles heads 2w,2w+1
#pragma unroll
  for (int hh = 0; hh < 2; ++hh) {
    const int h = w * 2 + hh;
    const int i = batch * 8 + h;
    float f0 = rowS[h * 128 + lane], f1 = rowS[h * 128 + 64 + lane];
    float m = fmaxf(f0, f1);
#pragma unroll
    for (int off = 32; off >= 1; off >>= 1) m = fmaxf(m, __shfl_xor(m, off, 64));
    const float e0 = expf(f0 - m), e1 = expf(f1 - m);
    float s = e0 + e1;
#pragma unroll
    for (int off = 32; off >= 1; off >>= 1) s += __shfl_xor(s, off, 64);
    const float inv = 1.0f / s;
    rowS[h * 128 + lane] = e0 * inv;       // same wave produces & consumes:
    rowS[h * 128 + 64 + lane] = e1 * inv;  // no barrier needed
    const float* __restrict__ qp = qh + (size_t)i * 8192 + lane;
    float acc2 = 0.0f;
#pragma unroll 8
    for (int b = 0; b < 128; ++b)
      acc2 = fmaf(rowS[h * 128 + b], qp[b * 64], acc2);
    attn[((size_t)a * 8 + batch) * 512 + h * 64 + lane] = acc2;
  }
}

// ---------------------------------------------------------------------------
// Kernel D: output projection, hi/lo MFMA; 64m x 32n tiles -> 256 blocks
// (was 128 at 64x64 — 0.5 blocks/CU, pure latency). Same verified fragment
// mapping; B staged by waves 2-3 only (32 rows), A by all threads.
// ---------------------------------------------------------------------------
__global__ __launch_bounds__(256)
void outmm_kernel(const float* __restrict__ Xa,
                  const float* __restrict__ W,
                  const float* __restrict__ bias,
                  float* __restrict__ out) {
  __shared__ __align__(16) unsigned short Ah[64 * 72];
  __shared__ __align__(16) unsigned short Al[64 * 72];
  __shared__ __align__(16) unsigned short Bh[32 * 72];
  __shared__ __align__(16) unsigned short Bl[32 * 72];
  const int n0 = blockIdx.x * 32;  // 0..480
  const int m0 = blockIdx.y * 64;  // 0..960
  const int tid = threadIdx.x;
  const int w = tid >> 6, lane = tid & 63;
  const int quad = lane >> 4, n15 = lane & 15;
  const int srow = tid >> 2;        // 0..63 (A rows)
  const int scol = (tid & 3) * 16;  // 0,16,32,48
  const bool doB = tid >= 128;
  const int brow = (tid & 127) >> 2;   // 0..31 (B rows, waves 2-3)
  const int bcol = (tid & 3) * 16;

  f32x4 acc[2];
#pragma unroll
  for (int nt = 0; nt < 2; ++nt) acc[nt] = (f32x4){0.f, 0.f, 0.f, 0.f};

  float4 av[4], bv[4];
#pragma unroll
  for (int jj = 0; jj < 4; ++jj)
    av[jj] = *(const float4*)&Xa[(m0 + srow) * 512 + scol + 4 * jj];
  if (doB) {
#pragma unroll
    for (int jj = 0; jj < 4; ++jj)
      bv[jj] = *(const float4*)&W[(n0 + brow) * 512 + bcol + 4 * jj];
  }

  for (int k0 = 0; k0 < 512; k0 += 64) {
    __syncthreads();
#pragma unroll
    for (int jj = 0; jj < 4; ++jj) {
      ushort4 hh, ll;
      split4(av[jj], hh, ll);
      *(ushort4*)&Ah[srow * 72 + scol + 4 * jj] = hh;
      *(ushort4*)&Al[srow * 72 + scol + 4 * jj] = ll;
    }
    if (doB) {
#pragma unroll
      for (int jj = 0; jj < 4; ++jj) {
        ushort4 hh, ll;
        split4(bv[jj], hh, ll);
        *(ushort4*)&Bh[brow * 72 + bcol + 4 * jj] = hh;
        *(ushort4*)&Bl[brow * 72 + bcol + 4 * jj] = ll;
      }
    }
    __syncthreads();
    if (k0 + 64 < 512) {
#pragma unroll
      for (int jj = 0; jj < 4; ++jj)
        av[jj] = *(const float4*)&Xa[(m0 + srow) * 512 + k0 + 64 + scol + 4 * jj];
      if (doB) {
#pragma unroll
        for (int jj = 0; jj < 4; ++jj)
          bv[jj] = *(const float4*)&W[(n0 + brow) * 512 + k0 + 64 + bcol + 4 * jj];
      }
    }
#pragma unroll
    for (int kk = 0; kk < 2; ++kk) {
      short8 ah = *(const short8*)&Ah[(w * 16 + n15) * 72 + kk * 32 + quad * 8];
      short8 al = *(const short8*)&Al[(w * 16 + n15) * 72 + kk * 32 + quad * 8];
#pragma unroll
      for (int nt = 0; nt < 2; ++nt) {
        short8 bh = *(const short8*)&Bh[(nt * 16 + n15) * 72 + kk * 32 + quad * 8];
        short8 bl = *(const short8*)&Bl[(nt * 16 + n15) * 72 + kk * 32 + quad * 8];
        acc[nt] = __builtin_amdgcn_mfma_f32_16x16x32_bf16(ah, bh, acc[nt], 0, 0, 0);
        acc[nt] = __builtin_amdgcn_mfma_f32_16x16x32_bf16(ah, bl, acc[nt], 0, 0, 0);
        acc[nt] = __builtin_amdgcn_mfma_f32_16x16x32_bf16(al, bh, acc[nt], 0, 0, 0);
      }
    }
  }

#pragma unroll
  for (int nt = 0; nt < 2; ++nt) {
    const int j = n0 + nt * 16 + n15;
    const float bj = bias[j];
#pragma unroll
    for (int r = 0; r < 4; ++r) {
      const int row = m0 + w * 16 + quad * 4 + r;
      out[(size_t)row * 512 + j] = acc[nt][r] + bj;
    }
  }
}

extern "C" void kernel_launch(void* const* d_in, const int* in_sizes, int n_in,
                              void* d_out, int out_size, void* d_ws,
                              size_t ws_size, hipStream_t stream) {
  const float* query = (const float*)d_in[0];
  const float* key   = (const float*)d_in[1];
  const float* value = (const float*)d_in[2];
  const float* cbias = (const float*)d_in[3];
  const float* W     = (const float*)d_in[4];
  const float* pb    = (const float*)d_in[5];
  const float* out_w = (const float*)d_in[6];
  const float* out_b = (const float*)d_in[7];
  float* out = (float*)d_out;

  float* ws = (float*)d_ws;
  float* qh = ws;                                        // 524288 f
  float* kh = ws + 524288;                               // 524288 f
  unsigned short* vh = (unsigned short*)(ws + 1048576);  // 524288 bf16
  float* attn = ws + 1048576 + 262144;                   // 524288 f

  projmm_kernel<<<dim3(24, 16), 256, 0, stream>>>(query, key, value, W, pb,
                                                  qh, kh, vh);
  score_kernel<<<1024, 256, 0, stream>>>(qh, kh, vh, cbias, attn);
  outmm_kernel<<<dim3(16, 16), 256, 0, stream>>>(attn, out_w, out_b, out);
}